// Round 2
// baseline (379.060 us; speedup 1.0000x reference)
//
#include <hip/hip_runtime.h>

// WindowAttention fused kernel for MI355X (gfx950) — round 2.
// B_=4096 windows, N=64 tokens, DIM=128, NH=4 heads, HD=32, nW=64.
// One block/window, one wave/head. S^T orientation: softmax + P/v stay in
// registers (half-wave shfl_xor(32) rebuilds MFMA frags); q/k overlay the
// x staging buffer -> LDS 40960 B = 4 blocks/CU.

typedef __bf16 bf16x8 __attribute__((ext_vector_type(8)));
typedef float f32x16 __attribute__((ext_vector_type(16)));

#define MFMA32(a, b, c) __builtin_amdgcn_mfma_f32_32x32x16_bf16(a, b, c, 0, 0, 0)
#define ATT_SCALE 0.17677669529663687f  // 32^-0.5

__device__ __forceinline__ unsigned short f2bf(float f) {
  union { float fv; unsigned u; } cv; cv.fv = f;
  unsigned r = cv.u + 0x7FFFu + ((cv.u >> 16) & 1u);  // RNE
  return (unsigned short)(r >> 16);
}
__device__ __forceinline__ unsigned pack2(float lo, float hi) {
  return (unsigned)f2bf(lo) | ((unsigned)f2bf(hi) << 16);
}
__device__ __forceinline__ bf16x8 frag_from(unsigned a, unsigned b, unsigned c, unsigned d) {
  union { unsigned u[4]; bf16x8 v; } t;
  t.u[0] = a; t.u[1] = b; t.u[2] = c; t.u[3] = d;
  return t.v;
}

// Rebuild an MFMA A/B fragment (K-tile kt of 16 tokens) from packed C-layout
// register pairs: own half-wave holds token blocks [16kt+4hl..+3] (pair A) and
// [16kt+8+4hl..+3] (pair B); shfl_xor(32) swaps the complementary blocks.
#define BUILD_FRAG(frag, arr, kt) {                                        \
  unsigned pA0 = arr[(kt) >> 1][4 * ((kt) & 1) + 0];                       \
  unsigned pA1 = arr[(kt) >> 1][4 * ((kt) & 1) + 1];                       \
  unsigned pB0 = arr[(kt) >> 1][4 * ((kt) & 1) + 2];                       \
  unsigned pB1 = arr[(kt) >> 1][4 * ((kt) & 1) + 3];                       \
  unsigned t0 = hl ? pA0 : pB0, t1 = hl ? pA1 : pB1;                       \
  unsigned r0 = (unsigned)__shfl_xor((int)t0, 32);                         \
  unsigned r1 = (unsigned)__shfl_xor((int)t1, 32);                         \
  frag = hl ? frag_from(r0, r1, pB0, pB1) : frag_from(pA0, pA1, r0, r1); }

// ---- single pre-kernel: CB^T build (256 blocks) + weight bf16 convert (32 blocks) ----
__global__ __launch_bounds__(256) void prep(
    const float* __restrict__ mask, const float* __restrict__ bias_table,
    const float* __restrict__ qkv_w, const float* __restrict__ proj_w,
    float* __restrict__ cbT, unsigned short* __restrict__ wq,
    unsigned short* __restrict__ wp) {
  int blk = blockIdx.x;
  if (blk < 256) {
    // cbT[w][h][j][i] = bias_table[relidx(i,j)][h] + mask[w][i][j]
    __shared__ float ms[64][65];
    int w = blk >> 2, h = blk & 3;
    const float* mw = mask + ((size_t)w << 12);
    #pragma unroll
    for (int it = 0; it < 16; ++it) {
      int idx = it * 256 + threadIdx.x;
      ms[idx >> 6][idx & 63] = mw[idx];
    }
    __syncthreads();
    float* cw = cbT + ((size_t)blk << 12);
    #pragma unroll
    for (int it = 0; it < 16; ++it) {
      int idx = it * 256 + threadIdx.x;
      int j = idx >> 6, i = idx & 63;   // i = query, j = key
      int ridx = ((i >> 3) - (j >> 3) + 7) * 15 + ((i & 7) - (j & 7) + 7);
      cw[idx] = ms[i][j] + bias_table[ridx * 4 + h];
    }
  } else {
    int t = (blk - 256) * 2048 + threadIdx.x;
    #pragma unroll
    for (int it = 0; it < 8; ++it, t += 256) {
      if (t < 384 * 128) wq[t] = f2bf(qkv_w[t]);
      else               wp[t - 384 * 128] = f2bf(proj_w[t - 384 * 128]);
    }
  }
}

// ---- fused window attention ----
__global__ __launch_bounds__(256, 4) void window_attn(
    const float* __restrict__ x, const float* __restrict__ qkv_b,
    const float* __restrict__ proj_b, const unsigned short* __restrict__ wq,
    const unsigned short* __restrict__ wp, const float* __restrict__ cbT,
    float* __restrict__ out, int nW) {
  // Phase 1: Xb[64][136] bf16 staging of x (17408 B, offset 0)
  // Phase 2: q/k per head at h*5120 shorts: q[64][40], k[64][40]  (40960 B)
  // Phase 3: Obuf[64][136] (17408 B, offset 0, overlays heads 0/1 q/k)
  __shared__ unsigned short L[20480];  // 40960 B -> 4 blocks/CU

  const int tid = threadIdx.x;
  const int h = tid >> 6, lane = tid & 63, l31 = lane & 31, hl = lane >> 5;
  const int b = blockIdx.x;
  const int w = b % nW;

  // ---- stage x[b] -> bf16 Xb, coalesced float4 ----
  const float* xb = x + (size_t)b * 8192;
  #pragma unroll
  for (int it = 0; it < 8; ++it) {
    int e = (it * 256 + tid) * 4;
    float4 v4 = *reinterpret_cast<const float4*>(xb + e);
    uint2 u; u.x = pack2(v4.x, v4.y); u.y = pack2(v4.z, v4.w);
    *reinterpret_cast<uint2*>(&L[(e >> 7) * 136 + (e & 127)]) = u;
  }
  __syncthreads();

  // ---- QKV GEMM: results held packed in regs (Xb still live) ----
  unsigned qpk[2][8], kpk[2][8], vpk[2][8];
  #pragma unroll
  for (int mt = 0; mt < 2; ++mt) {
    bf16x8 aF[8];
    #pragma unroll
    for (int kt = 0; kt < 8; ++kt)
      aF[kt] = *reinterpret_cast<const bf16x8*>(&L[(mt * 32 + l31) * 136 + kt * 16 + hl * 8]);
    #pragma unroll
    for (int s = 0; s < 3; ++s) {
      const int c = s * 128 + h * 32 + l31;
      const float bias = qkv_b[c];
      const unsigned short* wrow = wq + c * 128 + hl * 8;
      f32x16 acc;
      #pragma unroll
      for (int q = 0; q < 16; ++q) acc[q] = 0.0f;
      #pragma unroll
      for (int kt = 0; kt < 8; ++kt) {
        bf16x8 bF = *reinterpret_cast<const bf16x8*>(wrow + kt * 16);
        acc = MFMA32(aF[kt], bF, acc);
      }
      #pragma unroll
      for (int p = 0; p < 8; ++p) {
        float lo = acc[2 * p] + bias, hi = acc[2 * p + 1] + bias;
        if (s == 0) { lo *= ATT_SCALE; hi *= ATT_SCALE; qpk[mt][p] = pack2(lo, hi); }
        else if (s == 1) kpk[mt][p] = pack2(lo, hi);
        else             vpk[mt][p] = pack2(lo, hi);
      }
    }
  }
  __syncthreads();  // Xb dead -> q/k may overlay

  // ---- write q,k token-major [64][40] (private per head; same-wave reuse) ----
  unsigned short* qh = &L[h * 5120];
  unsigned short* kh = qh + 2560;
  #pragma unroll
  for (int mt = 0; mt < 2; ++mt)
    #pragma unroll
    for (int p = 0; p < 8; ++p) {
      int row = ((2 * p) & 3) + 8 * (p >> 1) + 4 * hl + 32 * mt;
      qh[row * 40 + l31]       = (unsigned short)(qpk[mt][p] & 0xFFFF);
      qh[(row + 1) * 40 + l31] = (unsigned short)(qpk[mt][p] >> 16);
      kh[row * 40 + l31]       = (unsigned short)(kpk[mt][p] & 0xFFFF);
      kh[(row + 1) * 40 + l31] = (unsigned short)(kpk[mt][p] >> 16);
    }

  // ---- S^T init = CB^T (coalesced; hidden behind LDS writes/reads) ----
  f32x16 sacc[2][2];  // [mtj (j-tiles)][nti (i-tiles)]
  const float* cbp = cbT + (((size_t)(w * 4 + h)) << 12);
  #pragma unroll
  for (int mtj = 0; mtj < 2; ++mtj)
    #pragma unroll
    for (int r = 0; r < 16; ++r) {
      int j = (r & 3) + 8 * (r >> 2) + 4 * hl + 32 * mtj;
      sacc[mtj][0][r] = cbp[j * 64 + l31];
      sacc[mtj][1][r] = cbp[j * 64 + 32 + l31];
    }

  // ---- S^T = k q^T : A=k[j][d], B[d][i]=q[i][d] ----
  #pragma unroll
  for (int kt = 0; kt < 2; ++kt) {
    bf16x8 a0 = *reinterpret_cast<const bf16x8*>(&kh[l31 * 40 + kt * 16 + hl * 8]);
    bf16x8 a1 = *reinterpret_cast<const bf16x8*>(&kh[(32 + l31) * 40 + kt * 16 + hl * 8]);
    bf16x8 b0 = *reinterpret_cast<const bf16x8*>(&qh[l31 * 40 + kt * 16 + hl * 8]);
    bf16x8 b1 = *reinterpret_cast<const bf16x8*>(&qh[(32 + l31) * 40 + kt * 16 + hl * 8]);
    sacc[0][0] = MFMA32(a0, b0, sacc[0][0]);
    sacc[0][1] = MFMA32(a0, b1, sacc[0][1]);
    sacc[1][0] = MFMA32(a1, b0, sacc[1][0]);
    sacc[1][1] = MFMA32(a1, b1, sacc[1][1]);
  }

  // ---- softmax over j for fixed i=nti*32+l31 (no max-sub: |logit| < ~8) ----
  float rinv[2];
  unsigned epk[2][2][8];  // [nti][mtj][pair]
  #pragma unroll
  for (int nti = 0; nti < 2; ++nti) {
    float e[2][16];
    float ssum = 0.0f;
    #pragma unroll
    for (int mtj = 0; mtj < 2; ++mtj)
      #pragma unroll
      for (int r = 0; r < 16; ++r) {
        float ev = __expf(sacc[mtj][nti][r]);
        e[mtj][r] = ev; ssum += ev;
      }
    ssum += __shfl_xor(ssum, 32);     // other 32 j's live in lane^32
    rinv[nti] = __builtin_amdgcn_rcpf(ssum);
    #pragma unroll
    for (int mtj = 0; mtj < 2; ++mtj)
      #pragma unroll
      for (int p = 0; p < 8; ++p)
        epk[nti][mtj][p] = pack2(e[mtj][2 * p], e[mtj][2 * p + 1]);
  }

  // ---- O^T = v^T P^T : A[d][j]=v[j][d] (from vpk), B[j][i]=P[i][j] (from epk) ----
  f32x16 oacc[2];
  #pragma unroll
  for (int nti = 0; nti < 2; ++nti)
    #pragma unroll
    for (int q = 0; q < 16; ++q) oacc[nti][q] = 0.0f;
  #pragma unroll
  for (int kt = 0; kt < 4; ++kt) {
    bf16x8 av;  BUILD_FRAG(av, vpk, kt);
    bf16x8 bp0; BUILD_FRAG(bp0, epk[0], kt);
    bf16x8 bp1; BUILD_FRAG(bp1, epk[1], kt);
    oacc[0] = MFMA32(av, bp0, oacc[0]);
    oacc[1] = MFMA32(av, bp1, oacc[1]);
  }

  __syncthreads();  // all q/k reads done -> Obuf may overlay

  // ---- normalize + write O[i][h*32+d] (pairs -> b32 stores) ----
  #pragma unroll
  for (int nti = 0; nti < 2; ++nti) {
    int i = nti * 32 + l31;
    #pragma unroll
    for (int p = 0; p < 8; ++p) {
      int d = ((2 * p) & 3) + 8 * (p >> 1) + 4 * hl;
      unsigned u = pack2(oacc[nti][2 * p] * rinv[nti], oacc[nti][2 * p + 1] * rinv[nti]);
      *reinterpret_cast<unsigned*>(&L[i * 136 + h * 32 + d]) = u;
    }
  }
  __syncthreads();  // O (all heads) ready

  // ---- out = O proj_w^T + proj_b : wave h -> out channels [h*32, h*32+32) ----
  {
    const int c = h * 32 + l31;
    const float pb = proj_b[c];
    const unsigned short* wrow = wp + c * 128 + hl * 8;
    bf16x8 bfr[8];
    #pragma unroll
    for (int kt = 0; kt < 8; ++kt)
      bfr[kt] = *reinterpret_cast<const bf16x8*>(wrow + kt * 16);
    float* ob = out + (size_t)b * 8192;
    #pragma unroll
    for (int mt = 0; mt < 2; ++mt) {
      f32x16 acc;
      #pragma unroll
      for (int q = 0; q < 16; ++q) acc[q] = 0.0f;
      #pragma unroll
      for (int kt = 0; kt < 8; ++kt) {
        bf16x8 aF = *reinterpret_cast<const bf16x8*>(&L[(mt * 32 + l31) * 136 + kt * 16 + hl * 8]);
        acc = MFMA32(aF, bfr[kt], acc);
      }
      #pragma unroll
      for (int r = 0; r < 16; ++r) {
        int row = (r & 3) + 8 * (r >> 2) + 4 * hl + 32 * mt;
        ob[row * 128 + c] = acc[r] + pb;
      }
    }
  }
}

extern "C" void kernel_launch(void* const* d_in, const int* in_sizes, int n_in,
                              void* d_out, int out_size, void* d_ws, size_t ws_size,
                              hipStream_t stream) {
  const float* x          = (const float*)d_in[0];
  const float* mask       = (const float*)d_in[1];
  const float* qkv_w      = (const float*)d_in[2];
  const float* qkv_b      = (const float*)d_in[3];
  const float* proj_w     = (const float*)d_in[4];
  const float* proj_b     = (const float*)d_in[5];
  const float* bias_table = (const float*)d_in[6];
  const int B_ = in_sizes[0] / 8192;   // 4096
  const int nW = in_sizes[1] / 4096;   // 64

  // ws carve: wq bf16 (98304 B) | wp bf16 (32768 B) | CB^T fp32 (nW*4*4096*4 B)
  unsigned short* wq = (unsigned short*)d_ws;
  unsigned short* wp = wq + 384 * 128;
  float* cbT = (float*)((char*)d_ws + 131072);

  prep<<<288, 256, 0, stream>>>(mask, bias_table, qkv_w, proj_w, cbT, wq, wp);
  window_attn<<<B_, 256, 0, stream>>>(x, qkv_b, proj_b, wq, wp, cbT, (float*)d_out, nW);
}